// Round 1
// baseline (958.290 us; speedup 1.0000x reference)
//
#include <hip/hip_runtime.h>
#include <math.h>

#define CHN 128
#define TT 16384
#define NBATCH 8
#define KCONST 196608      // 128*128*3*4
#define TILE_T 64
#define HALO 8
#define ROWS 80            // TILE_T + 2*HALO
#define LROW 136           // padded LDS row stride in ushorts (16B-aligned rows)

typedef __bf16 bf16x8 __attribute__((ext_vector_type(8)));
typedef float  f32x4  __attribute__((ext_vector_type(4)));

__device__ __forceinline__ unsigned short f2bf(float f) {
    union { float f; unsigned int u; } v; v.f = f;
    unsigned int u = v.u;
    u += 0x7fffu + ((u >> 16) & 1u);   // round-to-nearest-even
    return (unsigned short)(u >> 16);
}

__device__ __forceinline__ float gelu_exact(float x) {
    return 0.5f * x * (1.0f + erff(x * 0.70710678118654752f));
}

// ---------------- Kernel 1: conditioning net -> hbar (8 x 64) ----------------
__global__ __launch_bounds__(256) void k_cond(
    const float* __restrict__ cond, const float* __restrict__ w0,
    const float* __restrict__ b0, const float* __restrict__ w1,
    const float* __restrict__ b1, float* __restrict__ hbar)
{
    __shared__ float cS[80 * 32];
    __shared__ float h0S[64 * 32];
    __shared__ float h1S[64 * 32];
    int b = blockIdx.x;
    int tid = threadIdx.x;

    for (int idx = tid; idx < 80 * 32; idx += 256)
        cS[idx] = cond[b * 80 * 32 + idx];
    __syncthreads();

    // conv0: 80 -> 64, k=5, pad=2, gelu(exact)
    for (int idx = tid; idx < 64 * 32; idx += 256) {
        int oc = idx >> 5, t = idx & 31;
        float acc = b0[oc];
        const float* wrow = w0 + oc * 80 * 5;
        for (int ic = 0; ic < 80; ++ic) {
            const float* cr = cS + ic * 32;
            #pragma unroll
            for (int j = 0; j < 5; ++j) {
                int ttv = t - 2 + j;
                if (ttv >= 0 && ttv < 32) acc += wrow[ic * 5 + j] * cr[ttv];
            }
        }
        h0S[idx] = gelu_exact(acc);
    }
    __syncthreads();

    // conv1: 64 -> 64, k=3, pad=1, gelu(exact)
    for (int idx = tid; idx < 64 * 32; idx += 256) {
        int oc = idx >> 5, t = idx & 31;
        float acc = b1[oc];
        const float* wrow = w1 + oc * 64 * 3;
        for (int ic = 0; ic < 64; ++ic) {
            const float* hr = h0S + ic * 32;
            #pragma unroll
            for (int j = 0; j < 3; ++j) {
                int ttv = t - 1 + j;
                if (ttv >= 0 && ttv < 32) acc += wrow[ic * 3 + j] * hr[ttv];
            }
        }
        h1S[idx] = gelu_exact(acc);
    }
    __syncthreads();

    if (tid < 64) {
        float s = 0.f;
        #pragma unroll
        for (int t = 0; t < 32; ++t) s += h1S[tid * 32 + t];
        hbar[b * 64 + tid] = s * (1.0f / 32.0f);
    }
}

// ---- Kernel 2: kernels/biases. W[b][layer][o][tap*128+c] bf16, bmean fp32 ----
__global__ __launch_bounds__(256) void k_weights(
    const float* __restrict__ w2, const float* __restrict__ b2,
    const float* __restrict__ hbar,
    unsigned short* __restrict__ W, float* __restrict__ bmean)
{
    __shared__ float hS[8 * 64];
    int tid = threadIdx.x;
    for (int idx = tid; idx < 512; idx += 256) hS[idx] = hbar[idx];
    __syncthreads();

    int p = blockIdx.x * 256 + tid;
    if (p < 65536) {
        int i = p >> 14, r = p & 16383, o = r >> 7, c = r & 127;
        long jbase = (long)i * 49152 + o * 384 + c * 3;
        float acc[3][8];
        #pragma unroll
        for (int tp = 0; tp < 3; ++tp)
            #pragma unroll
            for (int b = 0; b < 8; ++b) acc[tp][b] = 0.f;
        for (int cc = 0; cc < 64; ++cc) {
            float wv0 = w2[(jbase + 0) * 64 + cc];
            float wv1 = w2[(jbase + 1) * 64 + cc];
            float wv2 = w2[(jbase + 2) * 64 + cc];
            #pragma unroll
            for (int b = 0; b < 8; ++b) {
                float h = hS[b * 64 + cc];
                acc[0][b] += wv0 * h;
                acc[1][b] += wv1 * h;
                acc[2][b] += wv2 * h;
            }
        }
        #pragma unroll
        for (int tp = 0; tp < 3; ++tp) {
            float bb = b2[jbase + tp];
            #pragma unroll
            for (int b = 0; b < 8; ++b) {
                W[(long)((b * 4 + i) * 128 + o) * 384 + tp * 128 + c] =
                    f2bf(acc[tp][b] + bb);
            }
        }
    } else if (p < 65536 + 512) {
        int q = p - 65536;
        long j = (long)KCONST + q;
        float acc[8];
        #pragma unroll
        for (int b = 0; b < 8; ++b) acc[b] = 0.f;
        for (int cc = 0; cc < 64; ++cc) {
            float wv = w2[j * 64 + cc];
            #pragma unroll
            for (int b = 0; b < 8; ++b) acc[b] += wv * hS[b * 64 + cc];
        }
        float bb = b2[j];
        int i = q >> 7, o = q & 127;
        #pragma unroll
        for (int b = 0; b < 8; ++b) bmean[(b * 4 + i) * 128 + o] = acc[b] + bb;
    }
}

// -------- Kernel 3: one dilated conv layer, MFMA bf16, fp32 residual ---------
__global__ __launch_bounds__(256) void k_conv(
    const float* __restrict__ src, float* __restrict__ dst,
    const unsigned short* __restrict__ W, const float* __restrict__ bmean,
    const float* __restrict__ alpha, int d, int layer, int last)
{
    __shared__ __align__(16) unsigned short xT[ROWS * LROW];

    int tid  = threadIdx.x;
    int lane = tid & 63;
    int wave = tid >> 6;
    int bx   = blockIdx.x;
    int b    = bx >> 8;
    int tile = bx & 255;
    int T0   = tile * TILE_T;

    int nrow = lane & 15;   // = m for A-frag, = n (t offset) for B-frag/C
    int quad = lane >> 4;

    // --- A-fragment preload: wave owns o0 = wave*32, all 12 K-steps ---
    int o0 = wave * 32;
    const unsigned short* Wb = W + (long)((b * 4 + layer) * 128) * 384;
    bf16x8 af[2][12];
    #pragma unroll
    for (int mt = 0; mt < 2; ++mt) {
        const unsigned short* wr = Wb + (long)(o0 + mt * 16 + nrow) * 384 + quad * 8;
        #pragma unroll
        for (int ks = 0; ks < 12; ++ks)
            af[mt][ks] = *(const bf16x8*)(wr + ks * 32);
    }

    // --- stage x tile (80 rows x 128 ch) into LDS as bf16, [t][c] layout ---
    const float* xb = src + (long)b * CHN * TT;
    {
        int tl = tid & 63;            // rows [0,64): per-wave coalesced rows
        int cb = tid >> 6;
        int tg = T0 - HALO + tl;
        #pragma unroll
        for (int k = 0; k < 32; ++k) {
            int c = cb + k * 4;
            float v = (tg >= 0 && tg < TT) ? xb[(long)c * TT + tg] : 0.f;
            xT[tl * LROW + c] = f2bf(v);
        }
        int tl2 = 64 + (tid & 15);    // rows [64,80)
        int cb2 = tid >> 4;
        int tg2 = T0 - HALO + tl2;
        #pragma unroll
        for (int k = 0; k < 8; ++k) {
            int c = cb2 + k * 16;
            float v = (tg2 >= 0 && tg2 < TT) ? xb[(long)c * TT + tg2] : 0.f;
            xT[tl2 * LROW + c] = f2bf(v);
        }
    }
    __syncthreads();

    // --- K-loop: kk = tap*128 + c, kstep of 32 never crosses a tap ---
    f32x4 acc[2][4];
    #pragma unroll
    for (int mt = 0; mt < 2; ++mt)
        #pragma unroll
        for (int nt = 0; nt < 4; ++nt)
            acc[mt][nt] = (f32x4){0.f, 0.f, 0.f, 0.f};

    #pragma unroll
    for (int ks = 0; ks < 12; ++ks) {
        const int jtap = ks >> 2;
        const int c0 = (ks & 3) * 32 + quad * 8;
        bf16x8 bf[4];
        #pragma unroll
        for (int nt = 0; nt < 4; ++nt) {
            int trow = nt * 16 + nrow + (jtap - 1) * d + HALO;
            bf[nt] = *(const bf16x8*)&xT[trow * LROW + c0];
        }
        #pragma unroll
        for (int mt = 0; mt < 2; ++mt)
            #pragma unroll
            for (int nt = 0; nt < 4; ++nt)
                acc[mt][nt] = __builtin_amdgcn_mfma_f32_16x16x32_bf16(
                    af[mt][ks], bf[nt], acc[mt][nt], 0, 0, 0);
    }

    // --- epilogue: bias + fp32 residual (+ final sin activation) ---
    const float* bm = bmean + (b * 4 + layer) * 128;
    #pragma unroll
    for (int mt = 0; mt < 2; ++mt) {
        #pragma unroll
        for (int r = 0; r < 4; ++r) {
            int o = o0 + mt * 16 + quad * 4 + r;   // C/D: row = quad*4 + reg
            float bias = bm[o];
            float av = alpha[o];
            long rowoff = ((long)b * CHN + o) * TT + T0;
            #pragma unroll
            for (int nt = 0; nt < 4; ++nt) {
                int t = nt * 16 + nrow;            // C/D: col = lane&15
                float xn = src[rowoff + t] + acc[mt][nt][r] + bias;
                if (last) {
                    float s = sinf(av * xn);
                    xn = xn + (1.0f / (av + 1e-8f)) * s * s;
                }
                dst[rowoff + t] = xn;
            }
        }
    }
}

__global__ __launch_bounds__(256) void k_copy(const float* __restrict__ src,
                                              float* __restrict__ dst, int n)
{
    int i = blockIdx.x * 256 + threadIdx.x;
    if (i < n) dst[i] = src[i];
}

extern "C" void kernel_launch(void* const* d_in, const int* in_sizes, int n_in,
                              void* d_out, int out_size, void* d_ws, size_t ws_size,
                              hipStream_t stream) {
    const float* x     = (const float*)d_in[0];
    const float* cond  = (const float*)d_in[1];
    const float* w0    = (const float*)d_in[2];
    const float* b0    = (const float*)d_in[3];
    const float* w1    = (const float*)d_in[4];
    const float* b1    = (const float*)d_in[5];
    const float* w2    = (const float*)d_in[6];
    const float* b2    = (const float*)d_in[7];
    const float* alpha = (const float*)d_in[8];
    float* out = (float*)d_out;

    char* ws = (char*)d_ws;
    unsigned short* W = (unsigned short*)ws;               // 3,145,728 B
    float* bmean = (float*)(ws + 3145728);                 // 16,384 B
    float* hbar  = (float*)(ws + 3162112);                 // 2,048 B
    float* xbuf  = (float*)(ws + 4194304);                 // 64 MiB (if avail)
    const size_t need_big = 4194304 + (size_t)NBATCH * CHN * TT * 4;

    k_cond<<<8, 256, 0, stream>>>(cond, w0, b0, w1, b1, hbar);
    k_weights<<<258, 256, 0, stream>>>(w2, b2, hbar, W, bmean);

    float* xin = (float*)x;   // harness restores d_in before every launch
    if (ws_size >= need_big) {
        // L0: in->out, L1: out->in, L2: in->xbuf, L3: xbuf->out (+epilogue)
        k_conv<<<2048, 256, 0, stream>>>(x,    out,  W, bmean, alpha, 1, 0, 0);
        k_conv<<<2048, 256, 0, stream>>>(out,  xin,  W, bmean, alpha, 2, 1, 0);
        k_conv<<<2048, 256, 0, stream>>>(xin,  xbuf, W, bmean, alpha, 4, 2, 0);
        k_conv<<<2048, 256, 0, stream>>>(xbuf, out,  W, bmean, alpha, 8, 3, 1);
    } else {
        // fallback without a 64MB scratch buffer: extra d2d copy at the end
        k_conv<<<2048, 256, 0, stream>>>(x,    out,  W, bmean, alpha, 1, 0, 0);
        k_conv<<<2048, 256, 0, stream>>>(out,  xin,  W, bmean, alpha, 2, 1, 0);
        k_conv<<<2048, 256, 0, stream>>>(xin,  out,  W, bmean, alpha, 4, 2, 0);
        k_conv<<<2048, 256, 0, stream>>>(out,  xin,  W, bmean, alpha, 8, 3, 1);
        int n = NBATCH * CHN * TT;
        k_copy<<<(n + 255) / 256, 256, 0, stream>>>(xin, out, n);
    }
}

// Round 2
// 566.626 us; speedup vs baseline: 1.6912x; 1.6912x over previous
//
#include <hip/hip_runtime.h>
#include <math.h>

#define CHN 128
#define TT 16384
#define NBATCH 8
#define KCONST 196608      // 128*128*3*4
#define TILE_T 64
#define HALO 8
#define ROWS 80            // TILE_T + 2*HALO
#define LROW 136           // padded LDS row stride in ushorts (16B-aligned rows)

typedef __bf16 bf16x8 __attribute__((ext_vector_type(8)));
typedef float  f32x4  __attribute__((ext_vector_type(4)));

__device__ __forceinline__ unsigned short f2bf(float f) {
    union { float f; unsigned int u; } v; v.f = f;
    unsigned int u = v.u;
    u += 0x7fffu + ((u >> 16) & 1u);   // round-to-nearest-even
    return (unsigned short)(u >> 16);
}

__device__ __forceinline__ float gelu_exact(float x) {
    return 0.5f * x * (1.0f + erff(x * 0.70710678118654752f));
}

// ------------- Kernel 1a: conv0 (80->64, k=5, pad=2) + gelu -> h0 -------------
// grid = 64 blocks: blockIdx = b*8 + ocgroup. One output per thread.
__global__ __launch_bounds__(256) void k_cond0(
    const float* __restrict__ cond, const float* __restrict__ w0,
    const float* __restrict__ b0, float* __restrict__ h0)
{
    __shared__ float cS[80 * 32];    // 10240 B
    __shared__ float wS[8 * 80 * 5]; // 12800 B
    __shared__ float bS[8];
    int b = blockIdx.x >> 3, g = blockIdx.x & 7;
    int tid = threadIdx.x;

    for (int idx = tid; idx < 80 * 32; idx += 256) cS[idx] = cond[b * 2560 + idx];
    for (int idx = tid; idx < 8 * 400; idx += 256) wS[idx] = w0[g * 3200 + idx];
    if (tid < 8) bS[tid] = b0[g * 8 + tid];
    __syncthreads();

    int oc = tid >> 5, t = tid & 31;
    float acc = bS[oc];
    const float* wr = wS + oc * 400;
    for (int ic = 0; ic < 80; ++ic) {
        const float* cr = cS + ic * 32;
        #pragma unroll
        for (int j = 0; j < 5; ++j) {
            int tv = t - 2 + j;
            if (tv >= 0 && tv < 32) acc += wr[ic * 5 + j] * cr[tv];
        }
    }
    h0[(b * 64 + g * 8 + oc) * 32 + t] = gelu_exact(acc);
}

// ------ Kernel 1b: conv1 (64->64, k=3, pad=1) + gelu + mean_t -> hbar --------
// grid = 64 blocks: blockIdx = b*8 + ocgroup. One (oc,t) per thread, then
// shfl-reduce over the 32 t-lanes.
__global__ __launch_bounds__(256) void k_cond1(
    const float* __restrict__ h0, const float* __restrict__ w1,
    const float* __restrict__ b1, float* __restrict__ hbar)
{
    __shared__ float hS[64 * 32];    // 8192 B
    __shared__ float wS[8 * 64 * 3]; // 6144 B
    __shared__ float bS[8];
    int b = blockIdx.x >> 3, g = blockIdx.x & 7;
    int tid = threadIdx.x;

    for (int idx = tid; idx < 64 * 32; idx += 256) hS[idx] = h0[b * 2048 + idx];
    for (int idx = tid; idx < 8 * 192; idx += 256) wS[idx] = w1[g * 1536 + idx];
    if (tid < 8) bS[tid] = b1[g * 8 + tid];
    __syncthreads();

    int oc = tid >> 5, t = tid & 31;
    float acc = bS[oc];
    const float* wr = wS + oc * 192;
    for (int ic = 0; ic < 64; ++ic) {
        const float* hr = hS + ic * 32;
        #pragma unroll
        for (int j = 0; j < 3; ++j) {
            int tv = t - 1 + j;
            if (tv >= 0 && tv < 32) acc += wr[ic * 3 + j] * hr[tv];
        }
    }
    float v = gelu_exact(acc);
    // reduce over t: lanes [0,32) and [32,64) are separate oc's; xor masks <32
    // stay within each half.
    #pragma unroll
    for (int off = 1; off < 32; off <<= 1) v += __shfl_xor(v, off, 64);
    if (t == 0) hbar[b * 64 + g * 8 + oc] = v * (1.0f / 32.0f);
}

// ---- Kernel 2: kernels/biases. W[b][layer][o][tap*128+c] bf16, bmean fp32 ----
// One thread per output row j of w2 (197632 rows). float4 reads of w2[j,:],
// 8-batch dot against hbar in LDS.
__global__ __launch_bounds__(256) void k_weights(
    const float* __restrict__ w2, const float* __restrict__ b2,
    const float* __restrict__ hbar,
    unsigned short* __restrict__ W, float* __restrict__ bmean)
{
    __shared__ float hS[8 * 64];
    int tid = threadIdx.x;
    for (int idx = tid; idx < 512; idx += 256) hS[idx] = hbar[idx];
    __syncthreads();

    long p = (long)blockIdx.x * 256 + tid;   // [0, 197632)
    const float4* row = (const float4*)(w2 + p * 64);
    float acc[8];
    #pragma unroll
    for (int bb = 0; bb < 8; ++bb) acc[bb] = 0.f;
    #pragma unroll
    for (int q = 0; q < 16; ++q) {
        float4 wv = row[q];
        #pragma unroll
        for (int bb = 0; bb < 8; ++bb) {
            const float* h = hS + bb * 64 + q * 4;
            acc[bb] += wv.x * h[0] + wv.y * h[1] + wv.z * h[2] + wv.w * h[3];
        }
    }
    float bias = b2[p];
    if (p < KCONST) {
        int i = (int)(p / 49152); int r = (int)(p % 49152);
        int o = r / 384; int m = r % 384; int c = m / 3; int tp = m % 3;
        #pragma unroll
        for (int bb = 0; bb < 8; ++bb)
            W[(long)((bb * 4 + i) * 128 + o) * 384 + tp * 128 + c] =
                f2bf(acc[bb] + bias);
    } else {
        int q = (int)(p - KCONST); int i = q >> 7, o = q & 127;
        #pragma unroll
        for (int bb = 0; bb < 8; ++bb)
            bmean[(bb * 4 + i) * 128 + o] = acc[bb] + bias;
    }
}

// -------- Kernel 3: one dilated conv layer, MFMA bf16, fp32 residual ---------
__global__ __launch_bounds__(256) void k_conv(
    const float* __restrict__ src, float* __restrict__ dst,
    const unsigned short* __restrict__ W, const float* __restrict__ bmean,
    const float* __restrict__ alpha, int d, int layer, int last)
{
    __shared__ __align__(16) unsigned short xT[ROWS * LROW];

    int tid  = threadIdx.x;
    int lane = tid & 63;
    int wave = tid >> 6;
    int bx   = blockIdx.x;
    int b    = bx >> 8;
    int tile = bx & 255;
    int T0   = tile * TILE_T;

    int nrow = lane & 15;   // = m for A-frag, = n (t offset) for B-frag/C
    int quad = lane >> 4;

    // --- A-fragment preload: wave owns o0 = wave*32, all 12 K-steps ---
    int o0 = wave * 32;
    const unsigned short* Wb = W + (long)((b * 4 + layer) * 128) * 384;
    bf16x8 af[2][12];
    #pragma unroll
    for (int mt = 0; mt < 2; ++mt) {
        const unsigned short* wr = Wb + (long)(o0 + mt * 16 + nrow) * 384 + quad * 8;
        #pragma unroll
        for (int ks = 0; ks < 12; ++ks)
            af[mt][ks] = *(const bf16x8*)(wr + ks * 32);
    }

    // --- stage x tile (80 rows x 128 ch) into LDS as bf16, [t][c] layout ---
    const float* xb = src + (long)b * CHN * TT;
    {
        int tl = tid & 63;            // rows [0,64): per-wave coalesced rows
        int cb = tid >> 6;
        int tg = T0 - HALO + tl;
        #pragma unroll
        for (int k = 0; k < 32; ++k) {
            int c = cb + k * 4;
            float v = (tg >= 0 && tg < TT) ? xb[(long)c * TT + tg] : 0.f;
            xT[tl * LROW + c] = f2bf(v);
        }
        int tl2 = 64 + (tid & 15);    // rows [64,80)
        int cb2 = tid >> 4;
        int tg2 = T0 - HALO + tl2;
        #pragma unroll
        for (int k = 0; k < 8; ++k) {
            int c = cb2 + k * 16;
            float v = (tg2 >= 0 && tg2 < TT) ? xb[(long)c * TT + tg2] : 0.f;
            xT[tl2 * LROW + c] = f2bf(v);
        }
    }
    __syncthreads();

    // --- K-loop: kk = tap*128 + c, kstep of 32 never crosses a tap ---
    f32x4 acc[2][4];
    #pragma unroll
    for (int mt = 0; mt < 2; ++mt)
        #pragma unroll
        for (int nt = 0; nt < 4; ++nt)
            acc[mt][nt] = (f32x4){0.f, 0.f, 0.f, 0.f};

    #pragma unroll
    for (int ks = 0; ks < 12; ++ks) {
        const int jtap = ks >> 2;
        const int c0 = (ks & 3) * 32 + quad * 8;
        bf16x8 bf[4];
        #pragma unroll
        for (int nt = 0; nt < 4; ++nt) {
            int trow = nt * 16 + nrow + (jtap - 1) * d + HALO;
            bf[nt] = *(const bf16x8*)&xT[trow * LROW + c0];
        }
        #pragma unroll
        for (int mt = 0; mt < 2; ++mt)
            #pragma unroll
            for (int nt = 0; nt < 4; ++nt)
                acc[mt][nt] = __builtin_amdgcn_mfma_f32_16x16x32_bf16(
                    af[mt][ks], bf[nt], acc[mt][nt], 0, 0, 0);
    }

    // --- epilogue: bias + fp32 residual (+ final sin activation) ---
    const float* bm = bmean + (b * 4 + layer) * 128;
    #pragma unroll
    for (int mt = 0; mt < 2; ++mt) {
        #pragma unroll
        for (int r = 0; r < 4; ++r) {
            int o = o0 + mt * 16 + quad * 4 + r;   // C/D: row = quad*4 + reg
            float bias = bm[o];
            float av = alpha[o];
            long rowoff = ((long)b * CHN + o) * TT + T0;
            #pragma unroll
            for (int nt = 0; nt < 4; ++nt) {
                int t = nt * 16 + nrow;            // C/D: col = lane&15
                float xn = src[rowoff + t] + acc[mt][nt][r] + bias;
                if (last) {
                    float s = sinf(av * xn);
                    xn = xn + (1.0f / (av + 1e-8f)) * s * s;
                }
                dst[rowoff + t] = xn;
            }
        }
    }
}

__global__ __launch_bounds__(256) void k_copy(const float* __restrict__ src,
                                              float* __restrict__ dst, int n)
{
    int i = blockIdx.x * 256 + threadIdx.x;
    if (i < n) dst[i] = src[i];
}

extern "C" void kernel_launch(void* const* d_in, const int* in_sizes, int n_in,
                              void* d_out, int out_size, void* d_ws, size_t ws_size,
                              hipStream_t stream) {
    const float* x     = (const float*)d_in[0];
    const float* cond  = (const float*)d_in[1];
    const float* w0    = (const float*)d_in[2];
    const float* b0    = (const float*)d_in[3];
    const float* w1    = (const float*)d_in[4];
    const float* b1    = (const float*)d_in[5];
    const float* w2    = (const float*)d_in[6];
    const float* b2    = (const float*)d_in[7];
    const float* alpha = (const float*)d_in[8];
    float* out = (float*)d_out;

    char* ws = (char*)d_ws;
    unsigned short* W = (unsigned short*)ws;               // 3,145,728 B
    float* bmean = (float*)(ws + 3145728);                 // 16,384 B
    float* hbar  = (float*)(ws + 3162112);                 // 2,048 B
    float* h0    = (float*)(ws + 3164160);                 // 65,536 B
    float* xbuf  = (float*)(ws + 4194304);                 // 64 MiB (if avail)
    const size_t need_big = 4194304 + (size_t)NBATCH * CHN * TT * 4;

    k_cond0<<<64, 256, 0, stream>>>(cond, w0, b0, h0);
    k_cond1<<<64, 256, 0, stream>>>(h0, w1, b1, hbar);
    k_weights<<<772, 256, 0, stream>>>(w2, b2, hbar, W, bmean);

    float* xin = (float*)x;   // harness restores d_in before every launch
    if (ws_size >= need_big) {
        // L0: in->out, L1: out->in, L2: in->xbuf, L3: xbuf->out (+epilogue)
        k_conv<<<2048, 256, 0, stream>>>(x,    out,  W, bmean, alpha, 1, 0, 0);
        k_conv<<<2048, 256, 0, stream>>>(out,  xin,  W, bmean, alpha, 2, 1, 0);
        k_conv<<<2048, 256, 0, stream>>>(xin,  xbuf, W, bmean, alpha, 4, 2, 0);
        k_conv<<<2048, 256, 0, stream>>>(xbuf, out,  W, bmean, alpha, 8, 3, 1);
    } else {
        // fallback without a 64MB scratch buffer: extra d2d copy at the end
        k_conv<<<2048, 256, 0, stream>>>(x,    out,  W, bmean, alpha, 1, 0, 0);
        k_conv<<<2048, 256, 0, stream>>>(out,  xin,  W, bmean, alpha, 2, 1, 0);
        k_conv<<<2048, 256, 0, stream>>>(xin,  out,  W, bmean, alpha, 4, 2, 0);
        k_conv<<<2048, 256, 0, stream>>>(out,  xin,  W, bmean, alpha, 8, 3, 1);
        int n = NBATCH * CHN * TT;
        k_copy<<<(n + 255) / 256, 256, 0, stream>>>(xin, out, n);
    }
}

// Round 3
// 469.958 us; speedup vs baseline: 2.0391x; 1.2057x over previous
//
#include <hip/hip_runtime.h>
#include <math.h>

#define CHN 128
#define TT 16384
#define NBATCH 8
#define KCONST 196608      // 128*128*3*4
#define TILE_T 128
#define HALO 8
#define ROWS 144           // TILE_T + 2*HALO
#define LROW 136           // padded LDS row stride in ushorts (16B-aligned rows)

typedef __bf16 bf16x8 __attribute__((ext_vector_type(8)));
typedef float  f32x4  __attribute__((ext_vector_type(4)));

__device__ __forceinline__ unsigned short f2bf(float f) {
    union { float f; unsigned int u; } v; v.f = f;
    unsigned int u = v.u;
    u += 0x7fffu + ((u >> 16) & 1u);   // round-to-nearest-even
    return (unsigned short)(u >> 16);
}

__device__ __forceinline__ float gelu_exact(float x) {
    return 0.5f * x * (1.0f + erff(x * 0.70710678118654752f));
}

// ------------- Kernel 1a: conv0 (80->64, k=5, pad=2) + gelu -> h0 -------------
__global__ __launch_bounds__(256) void k_cond0(
    const float* __restrict__ cond, const float* __restrict__ w0,
    const float* __restrict__ b0, float* __restrict__ h0)
{
    __shared__ float cS[80 * 32];
    __shared__ float wS[8 * 80 * 5];
    __shared__ float bS[8];
    int b = blockIdx.x >> 3, g = blockIdx.x & 7;
    int tid = threadIdx.x;

    for (int idx = tid; idx < 80 * 32; idx += 256) cS[idx] = cond[b * 2560 + idx];
    for (int idx = tid; idx < 8 * 400; idx += 256) wS[idx] = w0[g * 3200 + idx];
    if (tid < 8) bS[tid] = b0[g * 8 + tid];
    __syncthreads();

    int oc = tid >> 5, t = tid & 31;
    float acc = bS[oc];
    const float* wr = wS + oc * 400;
    for (int ic = 0; ic < 80; ++ic) {
        const float* cr = cS + ic * 32;
        #pragma unroll
        for (int j = 0; j < 5; ++j) {
            int tv = t - 2 + j;
            if (tv >= 0 && tv < 32) acc += wr[ic * 5 + j] * cr[tv];
        }
    }
    h0[(b * 64 + g * 8 + oc) * 32 + t] = gelu_exact(acc);
}

// ------ Kernel 1b: conv1 (64->64, k=3, pad=1) + gelu + mean_t -> hbar --------
__global__ __launch_bounds__(256) void k_cond1(
    const float* __restrict__ h0, const float* __restrict__ w1,
    const float* __restrict__ b1, float* __restrict__ hbar)
{
    __shared__ float hS[64 * 32];
    __shared__ float wS[8 * 64 * 3];
    __shared__ float bS[8];
    int b = blockIdx.x >> 3, g = blockIdx.x & 7;
    int tid = threadIdx.x;

    for (int idx = tid; idx < 64 * 32; idx += 256) hS[idx] = h0[b * 2048 + idx];
    for (int idx = tid; idx < 8 * 192; idx += 256) wS[idx] = w1[g * 1536 + idx];
    if (tid < 8) bS[tid] = b1[g * 8 + tid];
    __syncthreads();

    int oc = tid >> 5, t = tid & 31;
    float acc = bS[oc];
    const float* wr = wS + oc * 192;
    for (int ic = 0; ic < 64; ++ic) {
        const float* hr = hS + ic * 32;
        #pragma unroll
        for (int j = 0; j < 3; ++j) {
            int tv = t - 1 + j;
            if (tv >= 0 && tv < 32) acc += wr[ic * 3 + j] * hr[tv];
        }
    }
    float v = gelu_exact(acc);
    #pragma unroll
    for (int off = 1; off < 32; off <<= 1) v += __shfl_xor(v, off, 64);
    if (t == 0) hbar[b * 64 + g * 8 + oc] = v * (1.0f / 32.0f);
}

// ---- Kernel 2: kernels/biases. W[b][layer][o][tap*128+c] bf16, bmean fp32 ----
__global__ __launch_bounds__(256) void k_weights(
    const float* __restrict__ w2, const float* __restrict__ b2,
    const float* __restrict__ hbar,
    unsigned short* __restrict__ W, float* __restrict__ bmean)
{
    __shared__ float hS[8 * 64];
    int tid = threadIdx.x;
    for (int idx = tid; idx < 512; idx += 256) hS[idx] = hbar[idx];
    __syncthreads();

    long p = (long)blockIdx.x * 256 + tid;   // [0, 197632)
    const float4* row = (const float4*)(w2 + p * 64);
    float acc[8];
    #pragma unroll
    for (int bb = 0; bb < 8; ++bb) acc[bb] = 0.f;
    #pragma unroll
    for (int q = 0; q < 16; ++q) {
        float4 wv = row[q];
        #pragma unroll
        for (int bb = 0; bb < 8; ++bb) {
            const float* h = hS + bb * 64 + q * 4;
            acc[bb] += wv.x * h[0] + wv.y * h[1] + wv.z * h[2] + wv.w * h[3];
        }
    }
    float bias = b2[p];
    if (p < KCONST) {
        int i = (int)(p / 49152); int r = (int)(p % 49152);
        int o = r / 384; int m = r % 384; int c = m / 3; int tp = m % 3;
        #pragma unroll
        for (int bb = 0; bb < 8; ++bb)
            W[(long)((bb * 4 + i) * 128 + o) * 384 + tp * 128 + c] =
                f2bf(acc[bb] + bias);
    } else {
        int q = (int)(p - KCONST); int i = q >> 7, o = q & 127;
        #pragma unroll
        for (int bb = 0; bb < 8; ++bb)
            bmean[(bb * 4 + i) * 128 + o] = acc[bb] + bias;
    }
}

// -------- Kernel 3: one dilated conv layer, MFMA bf16, fp32 residual ---------
__global__ __launch_bounds__(256) void k_conv(
    const float* __restrict__ src, float* __restrict__ dst,
    const unsigned short* __restrict__ W, const float* __restrict__ bmean,
    const float* __restrict__ alpha, int d, int layer, int last)
{
    __shared__ __align__(16) unsigned short xT[ROWS * LROW];  // 39168 B

    int tid  = threadIdx.x;
    int lane = tid & 63;
    int wave = tid >> 6;
    int b    = blockIdx.x >> 7;
    int tile = blockIdx.x & 127;
    int T0   = tile * TILE_T;

    int nrow = lane & 15;
    int quad = lane >> 4;

    const float* xb = src + (long)b * CHN * TT;

    // --- stage x tile (144 rows x 128 ch) into LDS as bf16, [t][c] layout ---
    // Batched loads (16 independent in flight) to expose MLP.
    {
        int tl = tid & 127;           // rows [0,128)
        int ch = (tid >> 7) * 64;     // c-half
        int tg = T0 - HALO + tl;
        bool ok = (tg >= 0) && (tg < TT);
        #pragma unroll
        for (int kb = 0; kb < 4; ++kb) {
            float tmp[16];
            #pragma unroll
            for (int k = 0; k < 16; ++k) {
                int c = ch + kb * 16 + k;
                tmp[k] = ok ? xb[(long)c * TT + tg] : 0.f;
            }
            #pragma unroll
            for (int k = 0; k < 16; ++k)
                xT[tl * LROW + ch + kb * 16 + k] = f2bf(tmp[k]);
        }
        int tl2 = 128 + (tid & 15);   // rows [128,144)
        int cs  = (tid >> 4) * 8;
        int tg2 = T0 - HALO + tl2;
        bool ok2 = (tg2 >= 0) && (tg2 < TT);
        float tmp2[8];
        #pragma unroll
        for (int k = 0; k < 8; ++k)
            tmp2[k] = ok2 ? xb[(long)(cs + k) * TT + tg2] : 0.f;
        #pragma unroll
        for (int k = 0; k < 8; ++k)
            xT[tl2 * LROW + cs + k] = f2bf(tmp2[k]);
    }
    __syncthreads();

    const unsigned short* Wb = W + (long)((b * 4 + layer) * 128) * 384;
    const float* bm = bmean + (b * 4 + layer) * 128;
    int o0 = wave * 32;

    // --- mt serialized so only one 12-step A-fragment set (48 VGPRs) is live ---
    #pragma unroll 1
    for (int mt = 0; mt < 2; ++mt) {
        bf16x8 af[12];
        const unsigned short* wr = Wb + (long)(o0 + mt * 16 + nrow) * 384 + quad * 8;
        #pragma unroll
        for (int ks = 0; ks < 12; ++ks)
            af[ks] = *(const bf16x8*)(wr + ks * 32);

        #pragma unroll 1
        for (int chunk = 0; chunk < 2; ++chunk) {
            f32x4 acc[4];
            #pragma unroll
            for (int nt = 0; nt < 4; ++nt) acc[nt] = (f32x4){0.f, 0.f, 0.f, 0.f};

            #pragma unroll
            for (int ks = 0; ks < 12; ++ks) {
                const int jtap = ks >> 2;
                const int c0 = (ks & 3) * 32 + quad * 8;
                const int base = chunk * 64 + nrow + (jtap - 1) * d + HALO;
                #pragma unroll
                for (int nt = 0; nt < 4; ++nt) {
                    bf16x8 bf = *(const bf16x8*)&xT[(base + nt * 16) * LROW + c0];
                    acc[nt] = __builtin_amdgcn_mfma_f32_16x16x32_bf16(
                        af[ks], bf, acc[nt], 0, 0, 0);
                }
            }

            // epilogue: bias + fp32 residual (+ final sin activation)
            #pragma unroll
            for (int r = 0; r < 4; ++r) {
                int o = o0 + mt * 16 + quad * 4 + r;   // C/D: row = quad*4 + reg
                float bias = bm[o];
                float av = alpha[o];
                long rowoff = ((long)b * CHN + o) * TT + T0 + chunk * 64;
                #pragma unroll
                for (int nt = 0; nt < 4; ++nt) {
                    int t = nt * 16 + nrow;            // C/D: col = lane&15
                    float xn = src[rowoff + t] + acc[nt][r] + bias;
                    if (last) {
                        float s = sinf(av * xn);
                        xn = xn + (1.0f / (av + 1e-8f)) * s * s;
                    }
                    dst[rowoff + t] = xn;
                }
            }
        }
    }
}

__global__ __launch_bounds__(256) void k_copy(const float* __restrict__ src,
                                              float* __restrict__ dst, int n)
{
    int i = blockIdx.x * 256 + threadIdx.x;
    if (i < n) dst[i] = src[i];
}

extern "C" void kernel_launch(void* const* d_in, const int* in_sizes, int n_in,
                              void* d_out, int out_size, void* d_ws, size_t ws_size,
                              hipStream_t stream) {
    const float* x     = (const float*)d_in[0];
    const float* cond  = (const float*)d_in[1];
    const float* w0    = (const float*)d_in[2];
    const float* b0    = (const float*)d_in[3];
    const float* w1    = (const float*)d_in[4];
    const float* b1    = (const float*)d_in[5];
    const float* w2    = (const float*)d_in[6];
    const float* b2    = (const float*)d_in[7];
    const float* alpha = (const float*)d_in[8];
    float* out = (float*)d_out;

    char* ws = (char*)d_ws;
    unsigned short* W = (unsigned short*)ws;               // 3,145,728 B
    float* bmean = (float*)(ws + 3145728);                 // 16,384 B
    float* hbar  = (float*)(ws + 3162112);                 // 2,048 B
    float* h0    = (float*)(ws + 3164160);                 // 65,536 B
    float* xbuf  = (float*)(ws + 4194304);                 // 64 MiB (if avail)
    const size_t need_big = 4194304 + (size_t)NBATCH * CHN * TT * 4;

    k_cond0<<<64, 256, 0, stream>>>(cond, w0, b0, h0);
    k_cond1<<<64, 256, 0, stream>>>(h0, w1, b1, hbar);
    k_weights<<<772, 256, 0, stream>>>(w2, b2, hbar, W, bmean);

    float* xin = (float*)x;   // harness restores d_in before every launch
    if (ws_size >= need_big) {
        // L0: in->out, L1: out->in, L2: in->xbuf, L3: xbuf->out (+epilogue)
        k_conv<<<1024, 256, 0, stream>>>(x,    out,  W, bmean, alpha, 1, 0, 0);
        k_conv<<<1024, 256, 0, stream>>>(out,  xin,  W, bmean, alpha, 2, 1, 0);
        k_conv<<<1024, 256, 0, stream>>>(xin,  xbuf, W, bmean, alpha, 4, 2, 0);
        k_conv<<<1024, 256, 0, stream>>>(xbuf, out,  W, bmean, alpha, 8, 3, 1);
    } else {
        // fallback without a 64MB scratch buffer: extra d2d copy at the end
        k_conv<<<1024, 256, 0, stream>>>(x,    out,  W, bmean, alpha, 1, 0, 0);
        k_conv<<<1024, 256, 0, stream>>>(out,  xin,  W, bmean, alpha, 2, 1, 0);
        k_conv<<<1024, 256, 0, stream>>>(xin,  out,  W, bmean, alpha, 4, 2, 0);
        k_conv<<<1024, 256, 0, stream>>>(out,  xin,  W, bmean, alpha, 8, 3, 1);
        int n = NBATCH * CHN * TT;
        k_copy<<<(n + 255) / 256, 256, 0, stream>>>(xin, out, n);
    }
}

// Round 4
// 394.942 us; speedup vs baseline: 2.4264x; 1.1899x over previous
//
#include <hip/hip_runtime.h>
#include <math.h>

#define CHN 128
#define TT 16384
#define NBATCH 8
#define KCONST 196608      // 128*128*3*4
#define TILE_T 64
#define HALO 8
#define ROWS 80            // TILE_T + 2*HALO
#define LROW 136           // padded LDS row stride in ushorts (16B-aligned rows)

typedef __bf16 bf16x8 __attribute__((ext_vector_type(8)));
typedef float  f32x4  __attribute__((ext_vector_type(4)));

__device__ __forceinline__ unsigned short f2bf(float f) {
    union { float f; unsigned int u; } v; v.f = f;
    unsigned int u = v.u;
    u += 0x7fffu + ((u >> 16) & 1u);   // round-to-nearest-even
    return (unsigned short)(u >> 16);
}

__device__ __forceinline__ float gelu_exact(float x) {
    return 0.5f * x * (1.0f + erff(x * 0.70710678118654752f));
}

// ------------- Kernel 1a: conv0 (80->64, k=5, pad=2) + gelu -> h0 -------------
__global__ __launch_bounds__(256) void k_cond0(
    const float* __restrict__ cond, const float* __restrict__ w0,
    const float* __restrict__ b0, float* __restrict__ h0)
{
    __shared__ float cS[80 * 32];
    __shared__ float wS[8 * 80 * 5];
    __shared__ float bS[8];
    int b = blockIdx.x >> 3, g = blockIdx.x & 7;
    int tid = threadIdx.x;

    for (int idx = tid; idx < 80 * 32; idx += 256) cS[idx] = cond[b * 2560 + idx];
    for (int idx = tid; idx < 8 * 400; idx += 256) wS[idx] = w0[g * 3200 + idx];
    if (tid < 8) bS[tid] = b0[g * 8 + tid];
    __syncthreads();

    int oc = tid >> 5, t = tid & 31;
    float acc = bS[oc];
    const float* wr = wS + oc * 400;
    for (int ic = 0; ic < 80; ++ic) {
        const float* cr = cS + ic * 32;
        #pragma unroll
        for (int j = 0; j < 5; ++j) {
            int tv = t - 2 + j;
            if (tv >= 0 && tv < 32) acc += wr[ic * 5 + j] * cr[tv];
        }
    }
    h0[(b * 64 + g * 8 + oc) * 32 + t] = gelu_exact(acc);
}

// ------ Kernel 1b: conv1 (64->64, k=3, pad=1) + gelu + mean_t -> hbar --------
__global__ __launch_bounds__(256) void k_cond1(
    const float* __restrict__ h0, const float* __restrict__ w1,
    const float* __restrict__ b1, float* __restrict__ hbar)
{
    __shared__ float hS[64 * 32];
    __shared__ float wS[8 * 64 * 3];
    __shared__ float bS[8];
    int b = blockIdx.x >> 3, g = blockIdx.x & 7;
    int tid = threadIdx.x;

    for (int idx = tid; idx < 64 * 32; idx += 256) hS[idx] = h0[b * 2048 + idx];
    for (int idx = tid; idx < 8 * 192; idx += 256) wS[idx] = w1[g * 1536 + idx];
    if (tid < 8) bS[tid] = b1[g * 8 + tid];
    __syncthreads();

    int oc = tid >> 5, t = tid & 31;
    float acc = bS[oc];
    const float* wr = wS + oc * 192;
    for (int ic = 0; ic < 64; ++ic) {
        const float* hr = hS + ic * 32;
        #pragma unroll
        for (int j = 0; j < 3; ++j) {
            int tv = t - 1 + j;
            if (tv >= 0 && tv < 32) acc += wr[ic * 3 + j] * hr[tv];
        }
    }
    float v = gelu_exact(acc);
    #pragma unroll
    for (int off = 1; off < 32; off <<= 1) v += __shfl_xor(v, off, 64);
    if (t == 0) hbar[b * 64 + g * 8 + oc] = v * (1.0f / 32.0f);
}

// ---- Kernel 2: kernels/biases. W[b][layer][o][tap*128+c] bf16, bmean fp32 ----
__global__ __launch_bounds__(256) void k_weights(
    const float* __restrict__ w2, const float* __restrict__ b2,
    const float* __restrict__ hbar,
    unsigned short* __restrict__ W, float* __restrict__ bmean)
{
    __shared__ float hS[8 * 64];
    int tid = threadIdx.x;
    for (int idx = tid; idx < 512; idx += 256) hS[idx] = hbar[idx];
    __syncthreads();

    long p = (long)blockIdx.x * 256 + tid;   // [0, 197632)
    const float4* row = (const float4*)(w2 + p * 64);
    float acc[8];
    #pragma unroll
    for (int bb = 0; bb < 8; ++bb) acc[bb] = 0.f;
    #pragma unroll
    for (int q = 0; q < 16; ++q) {
        float4 wv = row[q];
        #pragma unroll
        for (int bb = 0; bb < 8; ++bb) {
            const float* h = hS + bb * 64 + q * 4;
            acc[bb] += wv.x * h[0] + wv.y * h[1] + wv.z * h[2] + wv.w * h[3];
        }
    }
    float bias = b2[p];
    if (p < KCONST) {
        int i = (int)(p / 49152); int r = (int)(p % 49152);
        int o = r / 384; int m = r % 384; int c = m / 3; int tp = m % 3;
        #pragma unroll
        for (int bb = 0; bb < 8; ++bb)
            W[(long)((bb * 4 + i) * 128 + o) * 384 + tp * 128 + c] =
                f2bf(acc[bb] + bias);
    } else {
        int q = (int)(p - KCONST); int i = q >> 7, o = q & 127;
        #pragma unroll
        for (int bb = 0; bb < 8; ++bb)
            bmean[(bb * 4 + i) * 128 + o] = acc[bb] + bias;
    }
}

// -------- Kernel 3: one dilated conv layer, MFMA bf16, fp32 residual ---------
__global__ __launch_bounds__(256, 5) void k_conv(
    const float* __restrict__ src, float* __restrict__ dst,
    const unsigned short* __restrict__ W, const float* __restrict__ bmean,
    const float* __restrict__ alpha, int d, int layer, int last)
{
    __shared__ __align__(16) unsigned short xT[ROWS * LROW];  // 21760 B

    int tid  = threadIdx.x;
    int lane = tid & 63;
    int wave = tid >> 6;
    int b    = blockIdx.x >> 8;
    int tile = blockIdx.x & 255;
    int T0   = tile * TILE_T;

    int nrow = lane & 15;
    int quad = lane >> 4;

    const float* xb = src + (long)b * CHN * TT;

    // --- stage x tile (80 rows x 128 ch) into LDS as bf16, [t][c] layout ---
    {
        int tl = tid & 63;            // rows [0,64): per-wave coalesced rows
        int cb = tid >> 6;
        int tg = T0 - HALO + tl;
        bool ok = (tg >= 0) && (tg < TT);
        #pragma unroll
        for (int half = 0; half < 2; ++half) {
            float tmp[16];
            #pragma unroll
            for (int k = 0; k < 16; ++k) {
                int c = cb + (half * 16 + k) * 4;
                tmp[k] = ok ? xb[(long)c * TT + tg] : 0.f;
            }
            #pragma unroll
            for (int k = 0; k < 16; ++k)
                xT[tl * LROW + cb + (half * 16 + k) * 4] = f2bf(tmp[k]);
        }
        int tl2 = 64 + (tid & 15);    // rows [64,80)
        int cb2 = tid >> 4;
        int tg2 = T0 - HALO + tl2;
        bool ok2 = (tg2 >= 0) && (tg2 < TT);
        float tmp2[8];
        #pragma unroll
        for (int k = 0; k < 8; ++k)
            tmp2[k] = ok2 ? xb[(long)(cb2 + k * 16) * TT + tg2] : 0.f;
        #pragma unroll
        for (int k = 0; k < 8; ++k)
            xT[tl2 * LROW + cb2 + k * 16] = f2bf(tmp2[k]);
    }
    __syncthreads();

    const unsigned short* Wb = W + (long)((b * 4 + layer) * 128) * 384;
    const float* bm = bmean + (b * 4 + layer) * 128;
    int o0 = wave * 32;

    // --- mt serialized; A-frags in 6-step chunks; residual prefetched ---
    #pragma unroll 1
    for (int mt = 0; mt < 2; ++mt) {
        // residual prefetch: independent of MFMAs, issued before compute
        float res[4][4];
        #pragma unroll
        for (int r = 0; r < 4; ++r) {
            int o = o0 + mt * 16 + quad * 4 + r;
            long rowoff = ((long)b * CHN + o) * TT + T0;
            #pragma unroll
            for (int nt = 0; nt < 4; ++nt)
                res[r][nt] = src[rowoff + nt * 16 + nrow];
        }

        const unsigned short* wr = Wb + (long)(o0 + mt * 16 + nrow) * 384 + quad * 8;
        f32x4 acc[4];
        #pragma unroll
        for (int nt = 0; nt < 4; ++nt) acc[nt] = (f32x4){0.f, 0.f, 0.f, 0.f};

        #pragma unroll 1
        for (int kh = 0; kh < 2; ++kh) {
            bf16x8 af[6];
            #pragma unroll
            for (int k = 0; k < 6; ++k)
                af[k] = *(const bf16x8*)(wr + (kh * 6 + k) * 32);
            #pragma unroll
            for (int k = 0; k < 6; ++k) {
                const int ks = kh * 6 + k;
                const int jtap = ks >> 2;
                const int c0 = (ks & 3) * 32 + quad * 8;
                const int base = nrow + (jtap - 1) * d + HALO;
                #pragma unroll
                for (int nt = 0; nt < 4; ++nt) {
                    bf16x8 bf = *(const bf16x8*)&xT[(base + nt * 16) * LROW + c0];
                    acc[nt] = __builtin_amdgcn_mfma_f32_16x16x32_bf16(
                        af[k], bf, acc[nt], 0, 0, 0);
                }
            }
        }

        // epilogue: bias + fp32 residual (+ final sin activation)
        #pragma unroll
        for (int r = 0; r < 4; ++r) {
            int o = o0 + mt * 16 + quad * 4 + r;   // C/D: row = quad*4 + reg
            float bias = bm[o];
            float av = alpha[o];
            long rowoff = ((long)b * CHN + o) * TT + T0;
            #pragma unroll
            for (int nt = 0; nt < 4; ++nt) {
                int t = nt * 16 + nrow;            // C/D: col = lane&15
                float xn = res[r][nt] + acc[nt][r] + bias;
                if (last) {
                    float s = sinf(av * xn);
                    xn = xn + (1.0f / (av + 1e-8f)) * s * s;
                }
                dst[rowoff + t] = xn;
            }
        }
    }
}

__global__ __launch_bounds__(256) void k_copy(const float* __restrict__ src,
                                              float* __restrict__ dst, int n)
{
    int i = blockIdx.x * 256 + threadIdx.x;
    if (i < n) dst[i] = src[i];
}

extern "C" void kernel_launch(void* const* d_in, const int* in_sizes, int n_in,
                              void* d_out, int out_size, void* d_ws, size_t ws_size,
                              hipStream_t stream) {
    const float* x     = (const float*)d_in[0];
    const float* cond  = (const float*)d_in[1];
    const float* w0    = (const float*)d_in[2];
    const float* b0    = (const float*)d_in[3];
    const float* w1    = (const float*)d_in[4];
    const float* b1    = (const float*)d_in[5];
    const float* w2    = (const float*)d_in[6];
    const float* b2    = (const float*)d_in[7];
    const float* alpha = (const float*)d_in[8];
    float* out = (float*)d_out;

    char* ws = (char*)d_ws;
    unsigned short* W = (unsigned short*)ws;               // 3,145,728 B
    float* bmean = (float*)(ws + 3145728);                 // 16,384 B
    float* hbar  = (float*)(ws + 3162112);                 // 2,048 B
    float* h0    = (float*)(ws + 3164160);                 // 65,536 B
    float* xbuf  = (float*)(ws + 4194304);                 // 64 MiB (if avail)
    const size_t need_big = 4194304 + (size_t)NBATCH * CHN * TT * 4;

    k_cond0<<<64, 256, 0, stream>>>(cond, w0, b0, h0);
    k_cond1<<<64, 256, 0, stream>>>(h0, w1, b1, hbar);
    k_weights<<<772, 256, 0, stream>>>(w2, b2, hbar, W, bmean);

    float* xin = (float*)x;   // harness restores d_in before every launch
    if (ws_size >= need_big) {
        // L0: in->out, L1: out->in, L2: in->xbuf, L3: xbuf->out (+epilogue)
        k_conv<<<2048, 256, 0, stream>>>(x,    out,  W, bmean, alpha, 1, 0, 0);
        k_conv<<<2048, 256, 0, stream>>>(out,  xin,  W, bmean, alpha, 2, 1, 0);
        k_conv<<<2048, 256, 0, stream>>>(xin,  xbuf, W, bmean, alpha, 4, 2, 0);
        k_conv<<<2048, 256, 0, stream>>>(xbuf, out,  W, bmean, alpha, 8, 3, 1);
    } else {
        // fallback without a 64MB scratch buffer: extra d2d copy at the end
        k_conv<<<2048, 256, 0, stream>>>(x,    out,  W, bmean, alpha, 1, 0, 0);
        k_conv<<<2048, 256, 0, stream>>>(out,  xin,  W, bmean, alpha, 2, 1, 0);
        k_conv<<<2048, 256, 0, stream>>>(xin,  out,  W, bmean, alpha, 4, 2, 0);
        k_conv<<<2048, 256, 0, stream>>>(out,  xin,  W, bmean, alpha, 8, 3, 1);
        int n = NBATCH * CHN * TT;
        k_copy<<<(n + 255) / 256, 256, 0, stream>>>(xin, out, n);
    }
}

// Round 5
// 364.676 us; speedup vs baseline: 2.6278x; 1.0830x over previous
//
#include <hip/hip_runtime.h>
#include <math.h>

#define CHN 128
#define TT 16384
#define NBATCH 8
#define KCONST 196608      // 128*128*3*4
#define TILE_T 64
#define GUARD 8
#define CRANGE 96          // computed range per layer: [T0-16, T0+80)
#define ROWS 112           // CRANGE + 2*GUARD, t = T0 - 24 + row
#define LROW 136           // padded LDS row stride in ushorts (16B-aligned rows)

typedef __bf16 bf16x8 __attribute__((ext_vector_type(8)));
typedef float  f32x4  __attribute__((ext_vector_type(4)));
typedef unsigned short u16x8 __attribute__((ext_vector_type(8)));
typedef unsigned short u16x4 __attribute__((ext_vector_type(4)));

__device__ __forceinline__ unsigned short f2bf(float f) {
    union { float f; unsigned int u; } v; v.f = f;
    unsigned int u = v.u;
    u += 0x7fffu + ((u >> 16) & 1u);   // round-to-nearest-even
    return (unsigned short)(u >> 16);
}
__device__ __forceinline__ float b2f(unsigned short h) {
    union { float f; unsigned int u; } v; v.u = ((unsigned int)h) << 16;
    return v.f;
}

__device__ __forceinline__ float gelu_exact(float x) {
    return 0.5f * x * (1.0f + erff(x * 0.70710678118654752f));
}

// ------------- Kernel 1a: conv0 (80->64, k=5, pad=2) + gelu -> h0 -------------
__global__ __launch_bounds__(256) void k_cond0(
    const float* __restrict__ cond, const float* __restrict__ w0,
    const float* __restrict__ b0, float* __restrict__ h0)
{
    __shared__ float cS[80 * 32];
    __shared__ float wS[8 * 80 * 5];
    __shared__ float bS[8];
    int b = blockIdx.x >> 3, g = blockIdx.x & 7;
    int tid = threadIdx.x;

    for (int idx = tid; idx < 80 * 32; idx += 256) cS[idx] = cond[b * 2560 + idx];
    for (int idx = tid; idx < 8 * 400; idx += 256) wS[idx] = w0[g * 3200 + idx];
    if (tid < 8) bS[tid] = b0[g * 8 + tid];
    __syncthreads();

    int oc = tid >> 5, t = tid & 31;
    float acc = bS[oc];
    const float* wr = wS + oc * 400;
    for (int ic = 0; ic < 80; ++ic) {
        const float* cr = cS + ic * 32;
        #pragma unroll
        for (int j = 0; j < 5; ++j) {
            int tv = t - 2 + j;
            if (tv >= 0 && tv < 32) acc += wr[ic * 5 + j] * cr[tv];
        }
    }
    h0[(b * 64 + g * 8 + oc) * 32 + t] = gelu_exact(acc);
}

// ------ Kernel 1b: conv1 (64->64, k=3, pad=1) + gelu + mean_t -> hbar --------
__global__ __launch_bounds__(256) void k_cond1(
    const float* __restrict__ h0, const float* __restrict__ w1,
    const float* __restrict__ b1, float* __restrict__ hbar)
{
    __shared__ float hS[64 * 32];
    __shared__ float wS[8 * 64 * 3];
    __shared__ float bS[8];
    int b = blockIdx.x >> 3, g = blockIdx.x & 7;
    int tid = threadIdx.x;

    for (int idx = tid; idx < 64 * 32; idx += 256) hS[idx] = h0[b * 2048 + idx];
    for (int idx = tid; idx < 8 * 192; idx += 256) wS[idx] = w1[g * 1536 + idx];
    if (tid < 8) bS[tid] = b1[g * 8 + tid];
    __syncthreads();

    int oc = tid >> 5, t = tid & 31;
    float acc = bS[oc];
    const float* wr = wS + oc * 192;
    for (int ic = 0; ic < 64; ++ic) {
        const float* hr = hS + ic * 32;
        #pragma unroll
        for (int j = 0; j < 3; ++j) {
            int tv = t - 1 + j;
            if (tv >= 0 && tv < 32) acc += wr[ic * 3 + j] * hr[tv];
        }
    }
    float v = gelu_exact(acc);
    #pragma unroll
    for (int off = 1; off < 32; off <<= 1) v += __shfl_xor(v, off, 64);
    if (t == 0) hbar[b * 64 + g * 8 + oc] = v * (1.0f / 32.0f);
}

// ---- Kernel 2: kernels/biases. LDS-staged coalesced w2 reads. ----
__global__ __launch_bounds__(256) void k_weights(
    const float* __restrict__ w2, const float* __restrict__ b2,
    const float* __restrict__ hbar,
    unsigned short* __restrict__ W, float* __restrict__ bmean)
{
    __shared__ float hS[8 * 64];
    __shared__ float buf[256 * 68];   // 256 rows x 64 floats, +4 pad
    int tid = threadIdx.x;
    for (int idx = tid; idx < 512; idx += 256) hS[idx] = hbar[idx];

    // stage this block's 256 w2 rows (64 KB) via coalesced float4 stream
    const float4* src4 = (const float4*)(w2 + (long)blockIdx.x * 16384);
    #pragma unroll
    for (int it = 0; it < 16; ++it) {
        int f = it * 256 + tid;
        float4 v = src4[f];
        int row = f >> 4, col = f & 15;
        *(float4*)&buf[row * 68 + col * 4] = v;
    }
    __syncthreads();

    long p = (long)blockIdx.x * 256 + tid;   // [0, 197632), exact
    const float* rowp = &buf[tid * 68];
    float acc[8];
    #pragma unroll
    for (int bb = 0; bb < 8; ++bb) acc[bb] = 0.f;
    #pragma unroll
    for (int q = 0; q < 16; ++q) {
        float4 wv = *(const float4*)&rowp[q * 4];
        #pragma unroll
        for (int bb = 0; bb < 8; ++bb) {
            const float* h = hS + bb * 64 + q * 4;
            acc[bb] += wv.x * h[0] + wv.y * h[1] + wv.z * h[2] + wv.w * h[3];
        }
    }
    float bias = b2[p];
    if (p < KCONST) {
        int i = (int)(p / 49152); int r = (int)(p % 49152);
        int o = r / 384; int m = r % 384; int c = m / 3; int tp = m % 3;
        #pragma unroll
        for (int bb = 0; bb < 8; ++bb)
            W[(long)((bb * 4 + i) * 128 + o) * 384 + tp * 128 + c] =
                f2bf(acc[bb] + bias);
    } else {
        int q = (int)(p - KCONST); int i = q >> 7, o = q & 127;
        #pragma unroll
        for (int bb = 0; bb < 8; ++bb)
            bmean[(bb * 4 + i) * 128 + o] = acc[bb] + bias;
    }
}

// ------ Kernel 3: ALL 4 dilated conv layers fused, signal lives in LDS ------
// LDS buffer: 112 rows (t = T0-24+row), hi/lo bf16 pair per element (the lo
// word carries the fp32 residual remainder so the carry chain stays ~fp32).
// All layers compute the same aligned 96-row range [T0-16,T0+80) (rows 8..104);
// stale guard rows only corrupt edge outputs that validity analysis discards:
// valid y3 ⊇ [T0-2, T0+66) ⊇ the stored [T0, T0+64).
__global__ __launch_bounds__(256, 2) void k_fused(
    const float* __restrict__ src, float* __restrict__ dst,
    const unsigned short* __restrict__ W, const float* __restrict__ bmean,
    const float* __restrict__ alpha)
{
    __shared__ __align__(16) unsigned short xhi[ROWS * LROW];  // 30464 B
    __shared__ __align__(16) unsigned short xlo[ROWS * LROW];  // 30464 B

    int tid  = threadIdx.x;
    int lane = tid & 63;
    int wave = tid >> 6;
    int b    = blockIdx.x >> 8;
    int tile = blockIdx.x & 255;
    int T0   = tile * TILE_T;

    int nrow = lane & 15;
    int quad = lane >> 4;
    int o0   = wave * 32;

    const float* xb = src + (long)b * CHN * TT;

    // --- stage x: each wave covers its 32-c slice over all 112 rows;
    //     lane->t (coalesced global), 8-wide c chunks -> b128 LDS writes ---
    {
        int cb = wave * 32;
        #pragma unroll 1
        for (int pass = 0; pass < 2; ++pass) {
            int tl = pass * 64 + lane;
            if (tl < ROWS) {
                int tg = T0 - 24 + tl;
                bool ok = (tg >= 0) && (tg < TT);
                #pragma unroll
                for (int kb = 0; kb < 4; ++kb) {
                    float v[8];
                    #pragma unroll
                    for (int k = 0; k < 8; ++k)
                        v[k] = ok ? xb[(long)(cb + kb * 8 + k) * TT + tg] : 0.f;
                    u16x8 h, l;
                    #pragma unroll
                    for (int k = 0; k < 8; ++k) {
                        h[k] = f2bf(v[k]);
                        l[k] = f2bf(v[k] - b2f(h[k]));
                    }
                    *(u16x8*)&xhi[tl * LROW + cb + kb * 8] = h;
                    *(u16x8*)&xlo[tl * LROW + cb + kb * 8] = l;
                }
            }
        }
    }

    // alpha for this lane's 8 output channels (layer-independent)
    float aval[2][4];
    #pragma unroll
    for (int mt = 0; mt < 2; ++mt)
        #pragma unroll
        for (int r = 0; r < 4; ++r)
            aval[mt][r] = alpha[o0 + mt * 16 + quad * 4 + r];

    __syncthreads();

    #pragma unroll 1
    for (int l = 0; l < 4; ++l) {
        const int d = 1 << l;
        const unsigned short* Wl = W + (long)((b * 4 + l) * 128) * 384;
        const float* bm = bmean + (b * 4 + l) * 128;

        // A-fragments for both 16-row m-tiles (96 VGPRs) -> B read once
        bf16x8 af[2][12];
        #pragma unroll
        for (int mt = 0; mt < 2; ++mt) {
            const unsigned short* wr =
                Wl + (long)(o0 + mt * 16 + nrow) * 384 + quad * 8;
            #pragma unroll
            for (int ks = 0; ks < 12; ++ks)
                af[mt][ks] = *(const bf16x8*)(wr + ks * 32);
        }
        float bias[2][4];
        #pragma unroll
        for (int mt = 0; mt < 2; ++mt)
            #pragma unroll
            for (int r = 0; r < 4; ++r)
                bias[mt][r] = bm[o0 + mt * 16 + quad * 4 + r];

        f32x4 acc[2][6];
        #pragma unroll
        for (int mt = 0; mt < 2; ++mt)
            #pragma unroll
            for (int nt = 0; nt < 6; ++nt)
                acc[mt][nt] = (f32x4){0.f, 0.f, 0.f, 0.f};

        // K-loop over kk = tap*128 + c; B-frag read once, feeds both mt
        #pragma unroll
        for (int ks = 0; ks < 12; ++ks) {
            const int c0 = (ks & 3) * 32 + quad * 8;
            const int roff = GUARD + nrow + ((ks >> 2) - 1) * d;
            #pragma unroll
            for (int nt = 0; nt < 6; ++nt) {
                bf16x8 bf = *(const bf16x8*)&xhi[(roff + nt * 16) * LROW + c0];
                acc[0][nt] = __builtin_amdgcn_mfma_f32_16x16x32_bf16(
                    af[0][ks], bf, acc[0][nt], 0, 0, 0);
                acc[1][nt] = __builtin_amdgcn_mfma_f32_16x16x32_bf16(
                    af[1][ks], bf, acc[1][nt], 0, 0, 0);
            }
        }

        // residual (hi+lo) + bias folded into acc, before the write barrier
        #pragma unroll
        for (int mt = 0; mt < 2; ++mt) {
            int obase = o0 + mt * 16 + quad * 4;
            #pragma unroll
            for (int nt = 0; nt < 6; ++nt) {
                int trow = GUARD + nt * 16 + nrow;
                u16x4 rh = *(const u16x4*)&xhi[trow * LROW + obase];
                u16x4 rl = *(const u16x4*)&xlo[trow * LROW + obase];
                #pragma unroll
                for (int r = 0; r < 4; ++r)
                    acc[mt][nt][r] += b2f(rh[r]) + b2f(rl[r]) + bias[mt][r];
            }
        }
        __syncthreads();   // all reads of layer l done before any write

        if (l < 3) {
            #pragma unroll
            for (int mt = 0; mt < 2; ++mt) {
                int obase = o0 + mt * 16 + quad * 4;
                #pragma unroll
                for (int nt = 0; nt < 6; ++nt) {
                    int trow = GUARD + nt * 16 + nrow;
                    int tg = T0 - 16 + nt * 16 + nrow;
                    bool ok = ((unsigned)tg < (unsigned)TT);
                    u16x4 h, lo4;
                    #pragma unroll
                    for (int r = 0; r < 4; ++r) {
                        float v = ok ? acc[mt][nt][r] : 0.f;
                        h[r]   = f2bf(v);
                        lo4[r] = f2bf(v - b2f(h[r]));
                    }
                    *(u16x4*)&xhi[trow * LROW + obase] = h;
                    *(u16x4*)&xlo[trow * LROW + obase] = lo4;
                }
            }
            __syncthreads();
        } else {
            // final layer: sin activation, store only the valid 64-t core
            #pragma unroll
            for (int mt = 0; mt < 2; ++mt) {
                #pragma unroll
                for (int r = 0; r < 4; ++r) {
                    int o = o0 + mt * 16 + quad * 4 + r;
                    float av = aval[mt][r];
                    long rowoff = ((long)b * CHN + o) * TT + T0;
                    #pragma unroll
                    for (int nt = 1; nt < 5; ++nt) {
                        int t = (nt - 1) * 16 + nrow;
                        float xn = acc[mt][nt][r];
                        float s = sinf(av * xn);
                        dst[rowoff + t] = xn + (1.0f / (av + 1e-8f)) * s * s;
                    }
                }
            }
        }
    }
}

extern "C" void kernel_launch(void* const* d_in, const int* in_sizes, int n_in,
                              void* d_out, int out_size, void* d_ws, size_t ws_size,
                              hipStream_t stream) {
    const float* x     = (const float*)d_in[0];
    const float* cond  = (const float*)d_in[1];
    const float* w0    = (const float*)d_in[2];
    const float* b0    = (const float*)d_in[3];
    const float* w1    = (const float*)d_in[4];
    const float* b1    = (const float*)d_in[5];
    const float* w2    = (const float*)d_in[6];
    const float* b2    = (const float*)d_in[7];
    const float* alpha = (const float*)d_in[8];
    float* out = (float*)d_out;

    char* ws = (char*)d_ws;
    unsigned short* W = (unsigned short*)ws;               // 3,145,728 B
    float* bmean = (float*)(ws + 3145728);                 // 16,384 B
    float* hbar  = (float*)(ws + 3162112);                 // 2,048 B
    float* h0    = (float*)(ws + 3164160);                 // 65,536 B

    k_cond0<<<64, 256, 0, stream>>>(cond, w0, b0, h0);
    k_cond1<<<64, 256, 0, stream>>>(h0, w1, b1, hbar);
    k_weights<<<772, 256, 0, stream>>>(w2, b2, hbar, W, bmean);
    k_fused<<<2048, 256, 0, stream>>>(x, out, W, bmean, alpha);
}